// Round 7
// baseline (152.118 us; speedup 1.0000x reference)
//
#include <hip/hip_runtime.h>

// ---------------------------------------------------------------------------
// MalConv fused: GEMM M=16000, K=4000, N=256 (W1||W2) bf16 MFMA 16x16x32,
// epilogue GLU+relu+segmented-max in registers, then tiny FC.
//
// Round-7: ZERO-barrier free-running K-loop (R3) + LDS-resident x (R6).
// Prologue: coalesced stage of x-tile (u16, 62.5 KB) + emb table (bf16) into
// LDS; one barrier; then 125 kt iterations with NO syncs and NO LDS writes:
//   per wave per kt: 2x ds_read_u16 (x, 2 iters ahead) -> 2x ds_read_b128
//   (emb row gather = the A fragment, 1 iter ahead) -> 8 MFMA; B fragments
//   global->reg, perfectly-coalesced 1KB/instr, depth-2 prefetch.
// Register GLU pairing (wave owns o and o+128): epilogue needs no LDS.
// ---------------------------------------------------------------------------

typedef __attribute__((ext_vector_type(8))) short short8;
typedef __attribute__((ext_vector_type(4))) float f32x4;

__device__ __forceinline__ unsigned short f2b(float f) {
    union { float f; unsigned u; } un;
    un.f = f;
    unsigned u = un.u;
    return (unsigned short)((u + 0x7FFFu + ((u >> 16) & 1u)) >> 16);  // RNE
}

#define KT_COUNT 125                              // K = 4000 = 125 * 32
#define WS_BBLK_BYTES (KT_COUNT * 256 * 32 * 2)   // 2,048,000 B bf16 weights
#define WS_MWS_OFF WS_BBLK_BYTES                  // 8*128 f32 max accumulator

// Coalesced repack: W1,W2 (fp32 [128][8][500]) -> bf16 Bblk[kt][o][j]
// (j = kl*8 + c, k = kt*4 + kl). Block = one o; thread = one kt. Also zeros
// m_ws.
__global__ __launch_bounds__(128) void prep_weights(
        const float* __restrict__ W1, const float* __restrict__ W2,
        unsigned short* __restrict__ Bblk, float* __restrict__ m_ws) {
    const int o  = blockIdx.x;                    // 0..255
    const int kt = threadIdx.x;                   // 0..127 (active < 125)
    if (kt < KT_COUNT) {
        const float* W = (o < 128) ? W1 : W2;
        const int oo = o & 127;
        unsigned short v[32];
#pragma unroll
        for (int c = 0; c < 8; ++c) {
            float4 f = *(const float4*)&W[oo * 4000 + c * 500 + kt * 4];
            v[c]      = f2b(f.x);
            v[8 + c]  = f2b(f.y);
            v[16 + c] = f2b(f.z);
            v[24 + c] = f2b(f.w);
        }
        unsigned short* dst = Bblk + kt * 8192 + o * 32;
#pragma unroll
        for (int q = 0; q < 4; ++q) {
            uint4 p;
            p.x = (unsigned)v[q * 8 + 0] | ((unsigned)v[q * 8 + 1] << 16);
            p.y = (unsigned)v[q * 8 + 2] | ((unsigned)v[q * 8 + 3] << 16);
            p.z = (unsigned)v[q * 8 + 4] | ((unsigned)v[q * 8 + 5] << 16);
            p.w = (unsigned)v[q * 8 + 6] | ((unsigned)v[q * 8 + 7] << 16);
            *(uint4*)(dst + q * 8) = p;
        }
    }
    if (blockIdx.x == 0)
        for (int i = threadIdx.x; i < 8 * 128; i += 128) m_ws[i] = 0.f;
}

// 250 WGs x 512 threads; WG tile 64M x 256N (=128 o-pairs).
// Wave w: mq=w>>2 (rows mq*32 + mi*16 + l16), nq=w&3 (32 o-pairs).
// acc[2][4]: mi = m 16-block; ni 0,1 = W1 cols, ni 2,3 = matching W2 cols.
__global__ __launch_bounds__(512, 2) void malconv_main(
        const int* __restrict__ x, const float* __restrict__ emb,
        const float* __restrict__ b1, const float* __restrict__ b2,
        const unsigned short* __restrict__ Bblk, float* __restrict__ m_ws) {
    __shared__ __align__(16) unsigned short embb[257 * 8];   // 4.1 KB
    __shared__ __align__(16) unsigned short xlds[64 * 500];  // 62.5 KB u16

    const int t = threadIdx.x;
    const int m0 = blockIdx.x * 64;

    // ---- prologue: emb -> LDS (bf16) and x-tile -> LDS (u16), coalesced ----
    for (int e = t; e < 257 * 8; e += 512) embb[e] = f2b(emb[e]);
    {
        const int4* xg = (const int4*)(x + m0 * 500);   // 8000 int4s
        for (int i = t; i < 8000; i += 512) {
            int4 v = xg[i];
            ushort4 s;
            s.x = (unsigned short)v.x; s.y = (unsigned short)v.y;
            s.z = (unsigned short)v.z; s.w = (unsigned short)v.w;
            *(ushort4*)&xlds[i * 4] = s;
        }
    }

    const int lane = t & 63, wave = t >> 6;
    const int quad = lane >> 4, l16 = lane & 15;
    const int mq   = wave >> 2, nq = wave & 3;

    // per-lane x addresses (u16 index into xlds) for the two A rows
    const int xb0 = (mq * 32 + l16) * 500 + quad;        // mi=0 row
    const int xb1 = xb0 + 16 * 500;                      // mi=1 row

    // B fragments: ni0: o=nq*32+l16, ni1: +16, ni2: +128 (W2), ni3: +144.
    const unsigned short* bbase = Bblk + (nq * 32 + l16) * 32 + quad * 8;

    f32x4 acc[2][4];
#pragma unroll
    for (int mi = 0; mi < 2; ++mi)
#pragma unroll
        for (int ni = 0; ni < 4; ++ni) {
            f32x4 z = {0.f, 0.f, 0.f, 0.f};
            acc[mi][ni] = z;
        }

    __syncthreads();   // the ONLY barrier in this kernel

    // ---- software-pipeline preamble ----
    // A gather for kt=0; x queue primed for kt=1 (xg) and kt=2 (xn);
    // B for kt=0 (bcur) and kt=1 (bnxt).
    unsigned short xv0 = xlds[xb0], xv1 = xlds[xb1];
    short8 acur0 = *(const short8*)&embb[xv0 * 8];
    short8 acur1 = *(const short8*)&embb[xv1 * 8];
    unsigned short xg0 = xlds[xb0 + 4],  xg1 = xlds[xb1 + 4];   // for kt=1
    unsigned short xn0 = xlds[xb0 + 8],  xn1 = xlds[xb1 + 8];   // for kt=2
    short8 bcur[4], bnxt[4], bfut[4];
#pragma unroll
    for (int ni = 0; ni < 4; ++ni) {
        const int off = (ni & 1) * 512 + (ni >> 1) * 4096;
        bcur[ni] = *(const short8*)(bbase + off);
        bnxt[ni] = *(const short8*)(bbase + 8192 + off);
    }

    for (int kt = 0; kt < KT_COUNT; ++kt) {
        // B prefetch for kt+2 (clamped; tail re-loads harmless)
        {
            int ktf = kt + 2; if (ktf > KT_COUNT - 1) ktf = KT_COUNT - 1;
            const unsigned short* bb = bbase + ktf * 8192;
            bfut[0] = *(const short8*)(bb);
            bfut[1] = *(const short8*)(bb + 512);
            bfut[2] = *(const short8*)(bb + 4096);
            bfut[3] = *(const short8*)(bb + 4608);
        }
        // A gather for kt+1 (x values read from LDS two iterations ago)
        short8 anxt0 = *(const short8*)&embb[xg0 * 8];
        short8 anxt1 = *(const short8*)&embb[xg1 * 8];
        // x refill for kt+3's gather (clamped)
        {
            int ktx = kt + 3; if (ktx > KT_COUNT - 1) ktx = KT_COUNT - 1;
            xg0 = xn0; xg1 = xn1;
            xn0 = xlds[xb0 + ktx * 4];
            xn1 = xlds[xb1 + ktx * 4];
        }
        // MFMA: 8 per wave per kt
#pragma unroll
        for (int ni = 0; ni < 4; ++ni) {
            acc[0][ni] = __builtin_amdgcn_mfma_f32_16x16x32_bf16(
                acur0, bcur[ni], acc[0][ni], 0, 0, 0);
            acc[1][ni] = __builtin_amdgcn_mfma_f32_16x16x32_bf16(
                acur1, bcur[ni], acc[1][ni], 0, 0, 0);
        }
        // rotate pipeline registers
        acur0 = anxt0; acur1 = anxt1;
#pragma unroll
        for (int ni = 0; ni < 4; ++ni) { bcur[ni] = bnxt[ni]; bnxt[ni] = bfut[ni]; }
    }

    // ---- epilogue: register GLU + segmented max (no barrier needed) ----
    const int b0 = m0 / 2000;
    const int bsplit = (b0 + 1) * 2000;          // first patch of batch b0+1
    const bool crosses = (m0 + 63) >= bsplit;
#pragma unroll
    for (int ni = 0; ni < 2; ++ni) {
        int o = nq * 32 + ni * 16 + l16;
        float bb1 = b1[o], bb2 = b2[o];
        float mx0 = 0.f, mx1 = 0.f;              // h >= 0 always
#pragma unroll
        for (int mi = 0; mi < 2; ++mi)
#pragma unroll
            for (int r = 0; r < 4; ++r) {
                int ml = mq * 32 + mi * 16 + quad * 4 + r;
                float g1 = acc[mi][ni][r] + bb1;       // W1 frag
                float g2 = acc[mi][ni + 2][r] + bb2;   // matching W2 frag
                float h = fmaxf(g1 / (1.f + __expf(-g2)), 0.f);
                if (m0 + ml >= bsplit) mx1 = fmaxf(mx1, h);
                else                   mx0 = fmaxf(mx0, h);
            }
        // reduce across the 4 quads (same o, different rows)
        mx0 = fmaxf(mx0, __shfl_xor(mx0, 16));
        mx0 = fmaxf(mx0, __shfl_xor(mx0, 32));
        mx1 = fmaxf(mx1, __shfl_xor(mx1, 16));
        mx1 = fmaxf(mx1, __shfl_xor(mx1, 32));
        if (quad == 0) {
            // nonneg floats: int compare == float compare
            atomicMax((int*)&m_ws[b0 * 128 + o], __float_as_int(mx0));
            if (crosses)
                atomicMax((int*)&m_ws[(b0 + 1) * 128 + o], __float_as_int(mx1));
        }
    }
}

// out[b][j] = sum_o m_ws[b][o] * fcW[j][o] + fcb[j]   (16 outputs)
__global__ void fc_kernel(const float* __restrict__ m_ws,
                          const float* __restrict__ fcW,
                          const float* __restrict__ fcb,
                          float* __restrict__ out) {
    int t = threadIdx.x;
    if (t < 16) {
        int b = t >> 1, j = t & 1;
        float s = 0.f;
        for (int o = 0; o < 128; ++o) s += m_ws[b * 128 + o] * fcW[j * 128 + o];
        out[t] = s + fcb[j];
    }
}

extern "C" void kernel_launch(void* const* d_in, const int* in_sizes, int n_in,
                              void* d_out, int out_size, void* d_ws, size_t ws_size,
                              hipStream_t stream) {
    const int*   x   = (const int*)d_in[0];     // [8, 1e6] values 0..256
    const float* emb = (const float*)d_in[1];   // [257, 8]
    const float* W1  = (const float*)d_in[2];   // [128, 8, 500]
    const float* b1  = (const float*)d_in[3];   // [128]
    const float* W2  = (const float*)d_in[4];   // [128, 8, 500]
    const float* b2  = (const float*)d_in[5];   // [128]
    const float* fcW = (const float*)d_in[6];   // [2, 128]
    const float* fcb = (const float*)d_in[7];   // [2]
    float* out = (float*)d_out;                 // [8, 2]

    unsigned short* Bblk = (unsigned short*)d_ws;
    float* m_ws = (float*)((char*)d_ws + WS_MWS_OFF);

    prep_weights<<<256, 128, 0, stream>>>(W1, W2, Bblk, m_ws);
    malconv_main<<<250, 512, 0, stream>>>(x, emb, b1, b2, Bblk, m_ws);
    fc_kernel<<<1, 64, 0, stream>>>(m_ws, fcW, fcb, out);
}